// Round 2
// baseline (6223.343 us; speedup 1.0000x reference)
//
#include <hip/hip_runtime.h>
#include <math.h>

// 2-layer LSTM, B=64, T=512, F=256, H=512, fp32 — persistent cooperative kernel.
// R7: pay the h broadcast per-XCD, not per-block. R6 (5252us) fit: step =
// 4.4us fixed + 0.244us/MB x 24MB of agent-coherent (L2-bypass) h reads.
// All 64 blocks/layer read the SAME h => 8-16x amplification the per-XCD L2
// can absorb. h stores stay sc1 write-through to MALL; h READS become plain
// cached loads, made safe by a per-step agent acquire fence (buffer_inv:
// invalidates L1+L2 clean lines) issued by ONE wave between two barriers.
// Every coherent read is post-fence, every L2 fill post-publication => no
// stale data survives. Slot polls stay on the sc1 atomic path (cached polls
// would spin forever on stale values). Also: 16B plain loads (1/4 request
// count of 4x8B atomics), layer0 x-GEMM hoisted pre-wait (no h dependency),
// layer0 K-chunks rebalanced 8/8 across K-half waves (was 4/12),
// launch_bounds(512,1) (1 block/CU: 128 blocks on 256 CUs).
// Precision scheme unchanged: h and W split hi+lo bf16, 3 MFMAs per K=32
// chunk per N-tile, fp32 accumulate; c-state in registers. h0 ring depth 4,
// h1 ring depth 2; slot protocol unchanged from R6.
//
// Partition: blocks[0,64)=layer0, [64,128)=layer1; block = 8 hidden units
// (32 gate rows = 2 MFMA N-tiles); 512 threads = 8 waves: wave = (mt m-tile
// of 16 batches, kh K-half). MFMA 16x16x32 bf16: A=h rows (lane&15=batch,
// quad*8+j=k), B=W (lane&15=gate col), C: row=quad*4+reg=batch, col=lane&15.

#define TT 512
#define FF 256
#define HH 512
#define NB 128

typedef __attribute__((ext_vector_type(4)))  float f32x4;
typedef __attribute__((ext_vector_type(8)))  short short8;
typedef __attribute__((ext_vector_type(16))) short short16;

__device__ __forceinline__ float sigmoidf_(float v){ return 1.0f/(1.0f+__expf(-v)); }

__device__ __forceinline__ unsigned short f2bf(float f){          // RTNE fp32->bf16
    unsigned u = __float_as_uint(f);
    u += 0x7FFFu + ((u>>16)&1u);
    return (unsigned short)(u>>16);
}
__device__ __forceinline__ float bf2f(unsigned short h){ return __uint_as_float(((unsigned)h)<<16); }

__device__ __forceinline__ unsigned long long ld8coh(const unsigned* p){
    return __hip_atomic_load((const unsigned long long*)p, __ATOMIC_RELAXED, __HIP_MEMORY_SCOPE_AGENT);
}
__device__ __forceinline__ void st4coh(unsigned* p, unsigned v){
    __hip_atomic_store(p, v, __ATOMIC_RELAXED, __HIP_MEMORY_SCOPE_AGENT);
}
__device__ __forceinline__ void stslot(int* p, int v){
    __hip_atomic_store(p, v, __ATOMIC_RELAXED, __HIP_MEMORY_SCOPE_AGENT);
}

union HU { int4 q2[2]; short16 v; };

__device__ __forceinline__ void split8(const float* v, short8& h8, short8& l8){
#pragma unroll
    for (int j=0;j<8;++j){
        const unsigned short hh = f2bf(v[j]);
        h8[j] = (short)hh;
        l8[j] = (short)f2bf(v[j]-bf2f(hh));
    }
}

#define MFMA(a,b,c) __builtin_amdgcn_mfma_f32_16x16x32_bf16((a),(b),(c),0,0,0)

struct SMem {
    short8 wlo[2*16*2*64];        // [kh][c:16][nt:2][quad*16+nn] — 64 KB
    float  part[2][4][16][33];    // [kh][mt][row=batch-in-tile][col=nt*16+nn]
};

template<int LAYER>
__device__ __forceinline__ void run(
    const float* __restrict__ x,
    const float* __restrict__ WA, const float* __restrict__ WB,
    const float* __restrict__ bi, const float* __restrict__ bh,
    unsigned* __restrict__ hp0, unsigned* __restrict__ hp1,
    float* __restrict__ out, int* __restrict__ slots,
    const int tile, SMem* sm)
{
    const int tid  = threadIdx.x;
    const int lane = tid & 63;
    const int wv   = __builtin_amdgcn_readfirstlane(tid>>6);
    const int mt   = wv & 3;              // m-tile: batches [16*mt, 16*mt+16)
    const int kh   = wv >> 2;             // K-half
    const int nn   = lane & 15;           // gate col / A batch row within tile
    const int quad = lane >> 4;           // k-octet within chunk
    const int b_m  = mt*16 + nn;          // this lane's A batch row
    const int SA   = (LAYER==0)?FF:HH;    // WA row stride

    // ---- one-time: W-hi B-fragments into registers; W-lo fragments into LDS ----
    // layer0: kh0 = 8 x-chunks + 8 h0-chunks (k 0..255); kh1 = 8 h0-chunks (k 256..511)
    // layer1: kh0 = 16 Wih1 chunks (h0); kh1 = 16 Whh1 chunks (h1)
    short8 wHi[2][16];
    {
#pragma unroll
        for (int nt=0; nt<2; ++nt){
            const int jg = ((nn>>2)<<9) + (tile<<3) + (nt<<2) + (nn&3);
            const float* rA = WA + (size_t)jg*SA;
            const float* rB = WB + (size_t)jg*HH;
            const int ncw = (LAYER==1) ? 16 : (kh==0 ? 16 : 8);
            for (int c=0;c<ncw;++c){
                const float* p;
                if (LAYER==1)    p = (kh ? rB : rA) + c*32 + quad*8;
                else if (kh==1)  p = rB + (c+8)*32 + quad*8;              // h0 k 256..511
                else             p = (c<8) ? (rA + c*32 + quad*8)         // 8 x-chunks
                                           : (rB + (c-8)*32 + quad*8);    // h0 k 0..255
                float v[8];
#pragma unroll
                for (int j=0;j<8;++j) v[j]=p[j];
                short8 lo;
                split8(v, wHi[nt][c], lo);
                if (mt==0) sm->wlo[((kh*16 + c)*2 + nt)*64 + quad*16 + nn] = lo;
            }
        }
    }

    // ---- epilogue thread state: bias regs + register-resident c ----
    const int b_e = tid>>3, ul = tid&7;   // thread -> (batch, unit-in-block)
    float br[4]; float creg = 0.f;
#pragma unroll
    for (int g=0; g<4; ++g){
        const int jgb = (g<<9) + (tile<<3) + ul;
        br[g] = bi[jgb] + bh[jgb];
    }

    // h chunk: plain cached 16B loads (fence-protected); shared A across both N-tiles
#define CHUNK_H(SRCP, CIDX) { \
        const unsigned* p_ = (SRCP); \
        HU u; u.q2[0] = *(const int4*)(p_); u.q2[1] = *(const int4*)(p_+4); \
        const short8 aH = __builtin_shufflevector(u.v,u.v,0,2,4,6,8,10,12,14); \
        const short8 aL = __builtin_shufflevector(u.v,u.v,1,3,5,7,9,11,13,15); \
        const short8 l0 = sm->wlo[((kh*16+(CIDX))*2+0)*64 + quad*16 + nn]; \
        const short8 l1 = sm->wlo[((kh*16+(CIDX))*2+1)*64 + quad*16 + nn]; \
        aH0 = MFMA(aH, wHi[0][CIDX], aH0); \
        aM0 = MFMA(aH, l0,           aM0); \
        aM0 = MFMA(aL, wHi[0][CIDX], aM0); \
        aH1 = MFMA(aH, wHi[1][CIDX], aH1); \
        aM1 = MFMA(aH, l1,           aM1); \
        aM1 = MFMA(aL, wHi[1][CIDX], aM1); }

    const int myblk = blockIdx.x;
    for (int s=0; s<=TT; ++s){
        const bool active = LAYER ? (s>0) : (s<TT);
        const int t = LAYER ? (s-1) : s;
        f32x4 aH0={0.f,0.f,0.f,0.f}, aM0={0.f,0.f,0.f,0.f};
        f32x4 aH1={0.f,0.f,0.f,0.f}, aM1={0.f,0.f,0.f,0.f};

        // ---- pre-wait: layer0 x-GEMM (x is immutable input — no dependency) ----
        if (LAYER==0 && active && kh==0){
            const float* xp = x + ((size_t)b_m*TT + t)*FF + quad*8;
#pragma unroll
            for (int c=0;c<8;++c){
                float v[8];
                const float4 a0 = *(const float4*)(xp + c*32);
                const float4 a1 = *(const float4*)(xp + c*32 + 4);
                v[0]=a0.x; v[1]=a0.y; v[2]=a0.z; v[3]=a0.w;
                v[4]=a1.x; v[5]=a1.y; v[6]=a1.z; v[7]=a1.w;
                short8 aH, aL; split8(v, aH, aL);
                const short8 l0 = sm->wlo[((kh*16+c)*2+0)*64 + quad*16 + nn];
                const short8 l1 = sm->wlo[((kh*16+c)*2+1)*64 + quad*16 + nn];
                aH0 = MFMA(aH, wHi[0][c], aH0);
                aM0 = MFMA(aH, l0,        aM0);
                aM0 = MFMA(aL, wHi[0][c], aM0);
                aH1 = MFMA(aH, wHi[1][c], aH1);
                aM1 = MFMA(aH, l1,        aM1);
                aM1 = MFMA(aL, wHi[1][c], aM1);
            }
        }

        // ---- dependency wait (sc1 atomic polls — must bypass caches) ----
        if (wv==0){
            const int tgt = (lane<32) ? s : ((LAYER==0) ? (s-2) : s);
            const int* sp = slots + 2*lane;          // lanes 0..31: L0 slots, 32..63: L1
            for(;;){
                const unsigned long long q = ld8coh((const unsigned*)sp);
                const int v0 = (int)(unsigned)(q);
                const int v1 = (int)(unsigned)(q>>32);
                if (__all((v0>=tgt)&(v1>=tgt))) break;
                __builtin_amdgcn_s_sleep(1);
            }
        }
        __syncthreads();
        // ---- one acquire fence per block: inv L1+L2 so plain h loads see MALL ----
        if (wv==0) __builtin_amdgcn_fence(__ATOMIC_ACQUIRE, "agent");
        __syncthreads();

        if (active){
            if (LAYER==1){
                // kh=0: h0[s-1] (ring slot (s-1)&3); kh=1: h1[s-2] (slot s&1)
                const unsigned* src = kh ? (hp1 + (s&1)*32768)
                                         : (hp0 + ((s-1)&3)*32768);
#pragma unroll
                for (int c=0;c<16;++c)
                    CHUNK_H(src + ((c*4+quad)*64 + b_m)*8, c);
            } else {
                const unsigned* src = hp0 + ((s+3)&3)*32768;   // h0[s-1]
                if (kh==0){
#pragma unroll
                    for (int c2=0;c2<8;++c2)                    // h0 k 0..255
                        CHUNK_H(src + ((c2*4+quad)*64 + b_m)*8, 8+c2);
                } else {
#pragma unroll
                    for (int c=0;c<8;++c)                       // h0 k 256..511
                        CHUNK_H(src + (((c+8)*4+quad)*64 + b_m)*8, c);
                }
            }

            // ---- combine K-halves via LDS, then fused gate epilogue ----
#pragma unroll
            for (int r=0;r<4;++r){
                sm->part[kh][mt][quad*4+r][nn]    = aH0[r]+aM0[r];
                sm->part[kh][mt][quad*4+r][16+nn] = aH1[r]+aM1[r];
            }
            __syncthreads();
            {
                const int mte = b_e>>4, mr = b_e&15;
                const int ntl = ul>>2,  uq = ul&3;
                float pre[4];
#pragma unroll
                for (int g=0; g<4; ++g){
                    const int col = ntl*16 + (g<<2) + uq;
                    pre[g] = sm->part[0][mte][mr][col] + sm->part[1][mte][mr][col] + br[g];
                }
                const float iv = sigmoidf_(pre[0]);
                const float fv = sigmoidf_(pre[1]);
                const float gv = tanhf(pre[2]);
                const float ov = sigmoidf_(pre[3]);
                creg = fv*creg + iv*gv;                      // c in a register
                const float hn = ov * tanhf(creg);
                const unsigned short hh = f2bf(hn);
                const unsigned short hl = f2bf(hn - bf2f(hh));
                const unsigned pk = ((unsigned)hl<<16) | (unsigned)hh;
                const int idx = (tile*64 + b_e)*8 + ul;      // hA[koct=tile][b][8] pairs
                if (LAYER==0) st4coh(hp0 + (s&3)*32768 + idx, pk);
                else {
                    st4coh(hp1 + ((s-1)&1)*32768 + idx, pk);
                    out[((size_t)b_e*TT + t)*HH + (tile*8 + ul)] = hn;  // fp32, plain cached
                }
            }
        }

        // ---- publish progress: vmcnt(0) drain in syncthreads acks coherent
        // h stores before the token store issues ----
        __syncthreads();
        if (tid==0) stslot(slots + myblk, s+1);
    }
#undef CHUNK_H
}

__global__ void __launch_bounds__(512,1) lstm_persist(
    const float* __restrict__ x,
    const float* __restrict__ Wih0, const float* __restrict__ Whh0,
    const float* __restrict__ bi0,  const float* __restrict__ bh0,
    const float* __restrict__ Wih1, const float* __restrict__ Whh1,
    const float* __restrict__ bi1,  const float* __restrict__ bh1,
    unsigned* hp0, unsigned* hp1, float* out, int* slots)
{
    __shared__ SMem sm;
    const int layer = blockIdx.x>>6, tile = blockIdx.x&63;
    if (layer==0) run<0>(x, Wih0, Whh0, bi0, bh0, hp0, hp1, out, slots, tile, &sm);
    else          run<1>(x, Wih1, Whh1, bi1, bh1, hp0, hp1, out, slots, tile, &sm);
}

extern "C" void kernel_launch(void* const* d_in, const int* in_sizes, int n_in,
                              void* d_out, int out_size, void* d_ws, size_t ws_size,
                              hipStream_t stream) {
    (void)in_sizes; (void)n_in; (void)out_size; (void)ws_size;
    const float* x    = (const float*)d_in[0];
    const float* Wih0 = (const float*)d_in[1];
    const float* Whh0 = (const float*)d_in[2];
    const float* bi0  = (const float*)d_in[3];
    const float* bh0  = (const float*)d_in[4];
    const float* Wih1 = (const float*)d_in[5];
    const float* Whh1 = (const float*)d_in[6];
    const float* bi1  = (const float*)d_in[7];
    const float* bh1  = (const float*)d_in[8];
    float* out = (float*)d_out;
    unsigned* ws = (unsigned*)d_ws;

    // ws (uints): hp0 ring[4][32768] | hp1 ring[2][32768] | slots[128]
    unsigned* hp0 = ws;                   // 4 slots x 128KB
    unsigned* hp1 = ws + 4*32768;         // 2 slots x 128KB
    int* slots    = (int*)(ws + 6*32768);

    hipMemsetAsync(d_ws, 0, (6*32768 + 128)*sizeof(unsigned), stream);

    void* args[] = {
        (void*)&x, (void*)&Wih0, (void*)&Whh0, (void*)&bi0, (void*)&bh0,
        (void*)&Wih1, (void*)&Whh1, (void*)&bi1, (void*)&bh1,
        (void*)&hp0, (void*)&hp1, (void*)&out, (void*)&slots
    };
    hipLaunchCooperativeKernel((const void*)lstm_persist, dim3(NB), dim3(512),
                               args, 0, stream);
}

// Round 9
// 2517.446 us; speedup vs baseline: 2.4721x; 2.4721x over previous
//
#include <hip/hip_runtime.h>
#include <math.h>

// 2-layer LSTM, B=64, T=512, F=256, H=512, fp32 — persistent cooperative kernel.
// R9 (resubmit — R8-round bench was infra failure, container died): R8 bisection.
// R8 (batch-split grid) FAILED correctness (absmax 1.1e-2 / 468 across two
// launches => data-dependent, race-like). Protocol/index audits all pass vs R7
// (which PASSED, validating pre-wait x-GEMM, lb(512,1), ring/slot protocol).
// The only unprecedented code pattern in R8: runtime-predicated unrolled
// register loops (if(c<kcnt) with per-wave 3/2 chunk splits) guarding weight-
// reg loads and MFMA clusters. R9 removes ALL predication via uniform roles:
//   L0: 24 chunks = 8 waves x exactly 3 (1 x-chunk wv pre-wait + h chunks
//       2wv,2wv+1 post-wait); L1: 8 waves x exactly 4 (wv<4: Wih1 chunks
//       (wv&3)*4+c on h0; wv>=4: Whh1 on h1). All register indices static.
// Everything else identical to R8: 4 bg x 32 tile_u x 2 layers = 256 blocks,
// block = 16 batches x 16 units (4 MFMA N-tiles), W hi+lo limbs in VGPRs
// (zero per-step weight traffic), LDS = 34KB 8-way K-combine only, same-bg
// 64-slot sync, h0 ring depth 4 / h1 depth 2, targets L0:{L0>=s, L1>=s-2},
// L1:{both>=s}. Coherent h traffic 6 MB/step (R6 was 24 @ 5252us).
// If R9 passes: R8's defect was predicated-role plumbing. If R9 fails ~1e-2:
// defect is in the shared restructure -> revert to R6 structure next.
// Precision: h & W hi+lo bf16, 3 MFMAs/chunk/tile (hi*hi, hi*lo, lo*hi),
// fp32 acc, c-state in registers. MFMA 16x16x32 bf16: A=h (lane&15=batch,
// quad*8+j=k), B=W (lane&15=gate col), C: row=quad*4+reg=batch, col=lane&15.

#define TT 512
#define FF 256
#define HH 512
#define NB 256

typedef __attribute__((ext_vector_type(4)))  float f32x4;
typedef __attribute__((ext_vector_type(8)))  short short8;
typedef __attribute__((ext_vector_type(16))) short short16;

__device__ __forceinline__ float sigmoidf_(float v){ return 1.0f/(1.0f+__expf(-v)); }

__device__ __forceinline__ unsigned short f2bf(float f){          // RTNE fp32->bf16
    unsigned u = __float_as_uint(f);
    u += 0x7FFFu + ((u>>16)&1u);
    return (unsigned short)(u>>16);
}
__device__ __forceinline__ float bf2f(unsigned short h){ return __uint_as_float(((unsigned)h)<<16); }

__device__ __forceinline__ unsigned long long ld8coh(const unsigned* p){
    return __hip_atomic_load((const unsigned long long*)p, __ATOMIC_RELAXED, __HIP_MEMORY_SCOPE_AGENT);
}
__device__ __forceinline__ int ld4coh(const int* p){
    return __hip_atomic_load(p, __ATOMIC_RELAXED, __HIP_MEMORY_SCOPE_AGENT);
}
__device__ __forceinline__ void st4coh(unsigned* p, unsigned v){
    __hip_atomic_store(p, v, __ATOMIC_RELAXED, __HIP_MEMORY_SCOPE_AGENT);
}
__device__ __forceinline__ void stslot(int* p, int v){
    __hip_atomic_store(p, v, __ATOMIC_RELAXED, __HIP_MEMORY_SCOPE_AGENT);
}

union HU { unsigned long long q[4]; short16 v; };

__device__ __forceinline__ void split8(const float* v, short8& h8, short8& l8){
#pragma unroll
    for (int j=0;j<8;++j){
        const unsigned short hh = f2bf(v[j]);
        h8[j] = (short)hh;
        l8[j] = (short)f2bf(v[j]-bf2f(hh));
    }
}

__device__ __forceinline__ void loadsplit(const float* p, short8& h8, short8& l8){
    float v[8];
#pragma unroll
    for (int j=0;j<8;++j) v[j]=p[j];
    split8(v, h8, l8);
}

#define MFMA(a,b,c) __builtin_amdgcn_mfma_f32_16x16x32_bf16((a),(b),(c),0,0,0)

struct SMem { float part[8][16][66]; };   // 8-way K-combine, ~34 KB

template<int LAYER>
__device__ __forceinline__ void run(
    const float* __restrict__ x,
    const float* __restrict__ WA, const float* __restrict__ WB,
    const float* __restrict__ bi, const float* __restrict__ bh,
    unsigned* __restrict__ hp0, unsigned* __restrict__ hp1,
    float* __restrict__ out, int* __restrict__ slots,
    const int bg, const int tile_u, SMem* sm)
{
    const int tid  = threadIdx.x;
    const int lane = tid & 63;
    const int wv   = __builtin_amdgcn_readfirstlane(tid>>6);  // K-slice index
    const int nn   = lane & 15;           // gate col / A batch row within tile
    const int quad = lane >> 4;           // k-octet within chunk
    const int bglob= bg*16 + nn;          // this lane's global batch row

    // ---- one-time: BOTH W limbs as B-fragments in registers, UNIFORM roles ----
    // L0 slots: 0 = x chunk wv (Wih0, SA=FF); 1,2 = h chunks 2wv,2wv+1 (Whh0)
    // L1 slots: 0..3 = chunks (wv&3)*4+c of (wv<4 ? Wih1 : Whh1)
    constexpr int NC = (LAYER==0) ? 3 : 4;
    short8 wHi[4][NC], wLo[4][NC];
#pragma unroll
    for (int nt=0;nt<4;++nt){
        const int jg = ((nn>>2)<<9) + (tile_u<<4) + (nt<<2) + (nn&3);
        if (LAYER==0){
            const float* rA = WA + (size_t)jg*FF;
            const float* rB = WB + (size_t)jg*HH;
            loadsplit(rA + wv*32 + quad*8, wHi[nt][0], wLo[nt][0]);
#pragma unroll
            for (int c=0;c<2;++c)
                loadsplit(rB + (2*wv+c)*32 + quad*8, wHi[nt][1+c], wLo[nt][1+c]);
        } else {
            const float* rw = ((wv<4) ? WA : WB) + (size_t)jg*HH;
#pragma unroll
            for (int c=0;c<4;++c)
                loadsplit(rw + ((wv&3)*4+c)*32 + quad*8, wHi[nt][c], wLo[nt][c]);
        }
    }

    // ---- epilogue thread state: bias regs + register-resident c ----
    const int b_e = tid>>4, ul = tid&15;        // (batch-in-group, unit-in-block)
    const int u_e = (tile_u<<4) + ul;           // global hidden unit
    float br[4]={0.f,0.f,0.f,0.f}; float creg=0.f;
    if (tid<256){
#pragma unroll
        for (int g=0; g<4; ++g) br[g] = bi[(g<<9)+u_e] + bh[(g<<9)+u_e];
    }

    const int myslot = bg*64 + LAYER*32 + tile_u;
    const f32x4 Z = {0.f,0.f,0.f,0.f};

    // h chunk: read octet OCT (batch bglob), 3 MFMAs per N-tile with slot SLOT
#define CHUNK_H(OCT, SLOT) { \
        const unsigned* p_ = src + ((size_t)((OCT))*64 + bglob)*8; \
        HU u; \
        u.q[0]=ld8coh(p_);   u.q[1]=ld8coh(p_+2); \
        u.q[2]=ld8coh(p_+4); u.q[3]=ld8coh(p_+6); \
        const short8 aH = __builtin_shufflevector(u.v,u.v,0,2,4,6,8,10,12,14); \
        const short8 aL = __builtin_shufflevector(u.v,u.v,1,3,5,7,9,11,13,15); \
        _Pragma("unroll") \
        for (int nt=0;nt<4;++nt){ \
            accH[nt]=MFMA(aH,wHi[nt][(SLOT)],accH[nt]); \
            accM[nt]=MFMA(aH,wLo[nt][(SLOT)],accM[nt]); \
            accM[nt]=MFMA(aL,wHi[nt][(SLOT)],accM[nt]); \
        } }

    for (int s=0; s<=TT; ++s){
        const bool active = LAYER ? (s>0) : (s<TT);
        const int t = LAYER ? (s-1) : s;
        f32x4 accH[4], accM[4];
#pragma unroll
        for (int nt=0;nt<4;++nt){ accH[nt]=Z; accM[nt]=Z; }

        // ---- pre-wait: layer0 x-GEMM, chunk wv (immutable input) ----
        if (LAYER==0 && active){
            const float* p = x + ((size_t)bglob*TT + t)*FF + wv*32 + quad*8;
            float v[8];
            const float4 a0 = *(const float4*)(p);
            const float4 a1 = *(const float4*)(p+4);
            v[0]=a0.x; v[1]=a0.y; v[2]=a0.z; v[3]=a0.w;
            v[4]=a1.x; v[5]=a1.y; v[6]=a1.z; v[7]=a1.w;
            short8 aH, aL; split8(v, aH, aL);
#pragma unroll
            for (int nt=0;nt<4;++nt){
                accH[nt]=MFMA(aH,wHi[nt][0],accH[nt]);
                accM[nt]=MFMA(aH,wLo[nt][0],accM[nt]);
                accM[nt]=MFMA(aL,wHi[nt][0],accM[nt]);
            }
        }

        // ---- dependency wait: only the 64 same-bg slots ----
        if (wv==0){
            const int tgt = (LAYER==0 && lane>=32) ? (s-2) : s;   // L1 WAR slack for L0
            const int* sp = slots + bg*64 + lane;  // lanes 0..31: L0, 32..63: L1
            while (!__all(ld4coh(sp) >= tgt)) __builtin_amdgcn_s_sleep(1);
        }
        __syncthreads();

        if (active){
            if (LAYER==0){
                const unsigned* src = hp0 + ((s+3)&3)*32768;       // h0[s-1]
#pragma unroll
                for (int c=0;c<2;++c)
                    CHUNK_H((2*wv+c)*4+quad, 1+c);
            } else {
                const unsigned* src = (wv<4) ? hp0 + ((s+3)&3)*32768   // h0[s-1]
                                             : hp1 + (s&1)*32768;      // h1[s-2]
#pragma unroll
                for (int c=0;c<4;++c)
                    CHUNK_H(((wv&3)*4+c)*4+quad, c);
            }

            // ---- 8-way K-combine via LDS, then fused gate epilogue ----
#pragma unroll
            for (int nt=0;nt<4;++nt)
#pragma unroll
                for (int r=0;r<4;++r)
                    sm->part[wv][quad*4+r][nt*16+nn] = accH[nt][r]+accM[nt][r];
            __syncthreads();
            if (tid<256){
                float pre[4];
#pragma unroll
                for (int g=0; g<4; ++g){
                    const int col = ((ul>>2)<<4) + (g<<2) + (ul&3);
                    float sum = br[g];
#pragma unroll
                    for (int w=0;w<8;++w) sum += sm->part[w][b_e][col];
                    pre[g]=sum;
                }
                const float iv = sigmoidf_(pre[0]);
                const float fv = sigmoidf_(pre[1]);
                const float gv = tanhf(pre[2]);
                const float ov = sigmoidf_(pre[3]);
                creg = fv*creg + iv*gv;                      // c in a register
                const float hn = ov * tanhf(creg);
                const unsigned short hh = f2bf(hn);
                const unsigned short hl = f2bf(hn - bf2f(hh));
                const unsigned pk = ((unsigned)hl<<16) | (unsigned)hh;
                const int bge = bg*16 + b_e;
                const int idx = ((u_e>>3)*64 + bge)*8 + (u_e&7);  // hA[koct][b][8] pairs
                if (LAYER==0) st4coh(hp0 + (s&3)*32768 + idx, pk);
                else {
                    st4coh(hp1 + ((s+1)&1)*32768 + idx, pk);     // h1[s-1] -> slot (s-1)&1
                    out[((size_t)bge*TT + t)*HH + u_e] = hn;     // fp32, plain cached
                }
            }
        }

        // ---- publish: vmcnt(0) drain in syncthreads acks h stores first ----
        __syncthreads();
        if (tid==0) stslot(slots + myslot, s+1);
    }
#undef CHUNK_H
}

__global__ void __launch_bounds__(512,1) lstm_persist(
    const float* __restrict__ x,
    const float* __restrict__ Wih0, const float* __restrict__ Whh0,
    const float* __restrict__ bi0,  const float* __restrict__ bh0,
    const float* __restrict__ Wih1, const float* __restrict__ Whh1,
    const float* __restrict__ bi1,  const float* __restrict__ bh1,
    unsigned* hp0, unsigned* hp1, float* out, int* slots)
{
    __shared__ SMem sm;
    const int layer = blockIdx.x>>7, lid = blockIdx.x&127;
    const int bg = lid>>5, tile_u = lid&31;
    if (layer==0) run<0>(x, Wih0, Whh0, bi0, bh0, hp0, hp1, out, slots, bg, tile_u, &sm);
    else          run<1>(x, Wih1, Whh1, bi1, bh1, hp0, hp1, out, slots, bg, tile_u, &sm);
}

extern "C" void kernel_launch(void* const* d_in, const int* in_sizes, int n_in,
                              void* d_out, int out_size, void* d_ws, size_t ws_size,
                              hipStream_t stream) {
    (void)in_sizes; (void)n_in; (void)out_size; (void)ws_size;
    const float* x    = (const float*)d_in[0];
    const float* Wih0 = (const float*)d_in[1];
    const float* Whh0 = (const float*)d_in[2];
    const float* bi0  = (const float*)d_in[3];
    const float* bh0  = (const float*)d_in[4];
    const float* Wih1 = (const float*)d_in[5];
    const float* Whh1 = (const float*)d_in[6];
    const float* bi1  = (const float*)d_in[7];
    const float* bh1  = (const float*)d_in[8];
    float* out = (float*)d_out;
    unsigned* ws = (unsigned*)d_ws;

    // ws (uints): hp0 ring[4][32768] | hp1 ring[2][32768] | slots[256]
    unsigned* hp0 = ws;                   // 4 slots x 128KB
    unsigned* hp1 = ws + 4*32768;         // 2 slots x 128KB
    int* slots    = (int*)(ws + 6*32768); // [bg:4][L0 tiles 0..31 | L1 tiles 0..31]

    hipMemsetAsync(d_ws, 0, (6*32768 + 256)*sizeof(unsigned), stream);

    void* args[] = {
        (void*)&x, (void*)&Wih0, (void*)&Whh0, (void*)&bi0, (void*)&bh0,
        (void*)&Wih1, (void*)&Whh1, (void*)&bi1, (void*)&bh1,
        (void*)&hp0, (void*)&hp1, (void*)&out, (void*)&slots
    };
    hipLaunchCooperativeKernel((const void*)lstm_persist, dim3(NB), dim3(512),
                               args, 0, stream);
}

// Round 11
// 2458.543 us; speedup vs baseline: 2.5313x; 1.0240x over previous
//
#include <hip/hip_runtime.h>
#include <math.h>

// 2-layer LSTM, B=64, T=512, F=256, H=512, fp32 — persistent cooperative kernel.
// R11: R10 post-mortem found a PROVABLE off-by-one in its split-wait: h1[s-2]
// is readable iff L1 tokens >= s (h1[sigma-1] stored at step sigma, token
// sigma+1 published). R10 checked L1>=s only AFTER the wv>=4 h1 reads ->
// stale h1[s-4] from the depth-2 ring on same-bg L1 skew -> intermittent
// 1.25e-2 (R8-like signature). Fix, per-layer waits:
//   L1: R9's full front wait restored (all 64 same-bg slots >= s) — gates
//       h0[s-1] read, h1[s-2] read, and h1-store WAR. No back wait.
//   L0: split kept — front = L0 slots >= s (gates h0[s-1] read; same-bg L0
//       WAR readers covered too); back = L1 slots >= s-2 before the h0 store
//       (gates L1's step-(s-3) read of h0[s-4]). L0 no longer front-stalls
//       on L1 stragglers.
// LOAD-FIRST kept (R10's other delta): all of a wave's coherent h loads
// (L1: 16 ld8, L0: 8) issue into named HU regs BEFORE any MFMA — pure
// read-reordering of already-guaranteed data, 4x in-flight bytes.
// Else identical to R9 (2517us PASSED): 4bg x 32tu x 2 layers = 256 blocks;
// block = 16 batches x 16 units (4 N-tiles); W hi+lo limbs in VGPRs (L0:
// 8 waves x 3 chunks {x:wv | h:2wv,2wv+1}, L1: 8 waves x 4 {(wv&3)*4+c of
// Wih1|Whh1}); LDS = 34KB 8-way K-combine; h0 ring depth 4, h1 depth 2;
// publish after store-drain barrier. Precision: h & W hi+lo bf16, 3 MFMAs/
// chunk/tile, fp32 acc, c in registers. MFMA 16x16x32 bf16: A=h
// (lane&15=batch, quad*8+j=k), B=W (lane&15=gate col), C: row=quad*4+reg,
// col=lane&15.

#define TT 512
#define FF 256
#define HH 512
#define NB 256

typedef __attribute__((ext_vector_type(4)))  float f32x4;
typedef __attribute__((ext_vector_type(8)))  short short8;
typedef __attribute__((ext_vector_type(16))) short short16;

__device__ __forceinline__ float sigmoidf_(float v){ return 1.0f/(1.0f+__expf(-v)); }

__device__ __forceinline__ unsigned short f2bf(float f){          // RTNE fp32->bf16
    unsigned u = __float_as_uint(f);
    u += 0x7FFFu + ((u>>16)&1u);
    return (unsigned short)(u>>16);
}
__device__ __forceinline__ float bf2f(unsigned short h){ return __uint_as_float(((unsigned)h)<<16); }

__device__ __forceinline__ unsigned long long ld8coh(const unsigned* p){
    return __hip_atomic_load((const unsigned long long*)p, __ATOMIC_RELAXED, __HIP_MEMORY_SCOPE_AGENT);
}
__device__ __forceinline__ int ld4coh(const int* p){
    return __hip_atomic_load(p, __ATOMIC_RELAXED, __HIP_MEMORY_SCOPE_AGENT);
}
__device__ __forceinline__ void st4coh(unsigned* p, unsigned v){
    __hip_atomic_store(p, v, __ATOMIC_RELAXED, __HIP_MEMORY_SCOPE_AGENT);
}
__device__ __forceinline__ void stslot(int* p, int v){
    __hip_atomic_store(p, v, __ATOMIC_RELAXED, __HIP_MEMORY_SCOPE_AGENT);
}

union HU { unsigned long long q[4]; short16 v; };

__device__ __forceinline__ void split8(const float* v, short8& h8, short8& l8){
#pragma unroll
    for (int j=0;j<8;++j){
        const unsigned short hh = f2bf(v[j]);
        h8[j] = (short)hh;
        l8[j] = (short)f2bf(v[j]-bf2f(hh));
    }
}

__device__ __forceinline__ void loadsplit(const float* p, short8& h8, short8& l8){
    float v[8];
#pragma unroll
    for (int j=0;j<8;++j) v[j]=p[j];
    split8(v, h8, l8);
}

#define MFMA(a,b,c) __builtin_amdgcn_mfma_f32_16x16x32_bf16((a),(b),(c),0,0,0)

struct SMem { float part[8][16][66]; };   // 8-way K-combine, ~34 KB

template<int LAYER>
__device__ __forceinline__ void run(
    const float* __restrict__ x,
    const float* __restrict__ WA, const float* __restrict__ WB,
    const float* __restrict__ bi, const float* __restrict__ bh,
    unsigned* __restrict__ hp0, unsigned* __restrict__ hp1,
    float* __restrict__ out, int* __restrict__ slots,
    const int bg, const int tile_u, SMem* sm)
{
    const int tid  = threadIdx.x;
    const int lane = tid & 63;
    const int wv   = __builtin_amdgcn_readfirstlane(tid>>6);  // K-slice index
    const int nn   = lane & 15;           // gate col / A batch row within tile
    const int quad = lane >> 4;           // k-octet within chunk
    const int bglob= bg*16 + nn;          // this lane's global batch row

    // ---- one-time: BOTH W limbs as B-fragments in registers, UNIFORM roles ----
    // L0 slots: 0 = x chunk wv (Wih0); 1,2 = h chunks 2wv,2wv+1 (Whh0)
    // L1 slots: 0..3 = chunks (wv&3)*4+c of (wv<4 ? Wih1 : Whh1)
    constexpr int NC = (LAYER==0) ? 3 : 4;
    short8 wHi[4][NC], wLo[4][NC];
#pragma unroll
    for (int nt=0;nt<4;++nt){
        const int jg = ((nn>>2)<<9) + (tile_u<<4) + (nt<<2) + (nn&3);
        if (LAYER==0){
            const float* rA = WA + (size_t)jg*FF;
            const float* rB = WB + (size_t)jg*HH;
            loadsplit(rA + wv*32 + quad*8, wHi[nt][0], wLo[nt][0]);
#pragma unroll
            for (int c=0;c<2;++c)
                loadsplit(rB + (2*wv+c)*32 + quad*8, wHi[nt][1+c], wLo[nt][1+c]);
        } else {
            const float* rw = ((wv<4) ? WA : WB) + (size_t)jg*HH;
#pragma unroll
            for (int c=0;c<4;++c)
                loadsplit(rw + ((wv&3)*4+c)*32 + quad*8, wHi[nt][c], wLo[nt][c]);
        }
    }

    // ---- epilogue thread state: bias regs + register-resident c ----
    const int b_e = tid>>4, ul = tid&15;        // (batch-in-group, unit-in-block)
    const int u_e = (tile_u<<4) + ul;           // global hidden unit
    float br[4]={0.f,0.f,0.f,0.f}; float creg=0.f;
    if (tid<256){
#pragma unroll
        for (int g=0; g<4; ++g) br[g] = bi[(g<<9)+u_e] + bh[(g<<9)+u_e];
    }

    const int myslot = bg*64 + LAYER*32 + tile_u;
    const f32x4 Z = {0.f,0.f,0.f,0.f};

#define LOADH(U, OCT) { \
        const unsigned* p_ = src + ((size_t)((OCT))*64 + bglob)*8; \
        U.q[0]=ld8coh(p_);   U.q[1]=ld8coh(p_+2); \
        U.q[2]=ld8coh(p_+4); U.q[3]=ld8coh(p_+6); }

#define MATHH(U, SLOT) { \
        const short8 aH = __builtin_shufflevector(U.v,U.v,0,2,4,6,8,10,12,14); \
        const short8 aL = __builtin_shufflevector(U.v,U.v,1,3,5,7,9,11,13,15); \
        _Pragma("unroll") \
        for (int nt=0;nt<4;++nt){ \
            accH[nt]=MFMA(aH,wHi[nt][(SLOT)],accH[nt]); \
            accM[nt]=MFMA(aH,wLo[nt][(SLOT)],accM[nt]); \
            accM[nt]=MFMA(aL,wHi[nt][(SLOT)],accM[nt]); \
        } }

    for (int s=0; s<=TT; ++s){
        const bool active = LAYER ? (s>0) : (s<TT);
        const int t = LAYER ? (s-1) : s;
        f32x4 accH[4], accM[4];
#pragma unroll
        for (int nt=0;nt<4;++nt){ accH[nt]=Z; accM[nt]=Z; }

        // ---- pre-wait: layer0 x-GEMM, chunk wv (immutable input) ----
        if (LAYER==0 && active){
            const float* p = x + ((size_t)bglob*TT + t)*FF + wv*32 + quad*8;
            float v[8];
            const float4 a0 = *(const float4*)(p);
            const float4 a1 = *(const float4*)(p+4);
            v[0]=a0.x; v[1]=a0.y; v[2]=a0.z; v[3]=a0.w;
            v[4]=a1.x; v[5]=a1.y; v[6]=a1.z; v[7]=a1.w;
            short8 aH, aL; split8(v, aH, aL);
#pragma unroll
            for (int nt=0;nt<4;++nt){
                accH[nt]=MFMA(aH,wHi[nt][0],accH[nt]);
                accM[nt]=MFMA(aH,wLo[nt][0],accM[nt]);
                accM[nt]=MFMA(aL,wHi[nt][0],accM[nt]);
            }
        }

        // ---- FRONT wait ----
        // L0: L0 slots >= s (gates its only read, h0[s-1]).
        // L1: ALL 64 slots >= s (h0[s-1] read, h1[s-2] read, h1-store WAR).
        if (wv==0){
            if (LAYER==0){
                const int* sp = slots + bg*64 + (lane&31);
                while (!__all(ld4coh(sp) >= s)) __builtin_amdgcn_s_sleep(1);
            } else {
                const int* sp = slots + bg*64 + lane;
                while (!__all(ld4coh(sp) >= s)) __builtin_amdgcn_s_sleep(1);
            }
        }
        __syncthreads();

        if (active){
            if (LAYER==0){
                const unsigned* src = hp0 + ((s+3)&3)*32768;       // h0[s-1]
                HU u0,u1;                                          // LOAD-FIRST
                LOADH(u0,(2*wv+0)*4+quad);
                LOADH(u1,(2*wv+1)*4+quad);
                MATHH(u0,1); MATHH(u1,2);
            } else {
                const unsigned* src = (wv<4) ? hp0 + ((s+3)&3)*32768   // h0[s-1]
                                             : hp1 + (s&1)*32768;      // h1[s-2]
                HU u0,u1,u2,u3;                                    // LOAD-FIRST
                LOADH(u0,((wv&3)*4+0)*4+quad);
                LOADH(u1,((wv&3)*4+1)*4+quad);
                LOADH(u2,((wv&3)*4+2)*4+quad);
                LOADH(u3,((wv&3)*4+3)*4+quad);
                MATHH(u0,0); MATHH(u1,1); MATHH(u2,2); MATHH(u3,3);
            }

            // ---- part writes for 8-way K-combine ----
#pragma unroll
            for (int nt=0;nt<4;++nt)
#pragma unroll
                for (int r=0;r<4;++r)
                    sm->part[wv][quad*4+r][nt*16+nn] = accH[nt][r]+accM[nt][r];
        }

        // ---- BACK wait (L0 only): h0-store WAR vs L1's read of h0[s-4] ----
        if (LAYER==0 && wv==0){
            const int* sp2 = slots + bg*64 + 32 + (lane&31);  // L1 slots
            while (!__all(ld4coh(sp2) >= s-2)) __builtin_amdgcn_s_sleep(1);
        }
        __syncthreads();

        if (active && tid<256){
            float pre[4];
#pragma unroll
            for (int g=0; g<4; ++g){
                const int col = ((ul>>2)<<4) + (g<<2) + (ul&3);
                float sum = br[g];
#pragma unroll
                for (int w=0;w<8;++w) sum += sm->part[w][b_e][col];
                pre[g]=sum;
            }
            const float iv = sigmoidf_(pre[0]);
            const float fv = sigmoidf_(pre[1]);
            const float gv = tanhf(pre[2]);
            const float ov = sigmoidf_(pre[3]);
            creg = fv*creg + iv*gv;                      // c in a register
            const float hn = ov * tanhf(creg);
            const unsigned short hh = f2bf(hn);
            const unsigned short hl = f2bf(hn - bf2f(hh));
            const unsigned pk = ((unsigned)hl<<16) | (unsigned)hh;
            const int bge = bg*16 + b_e;
            const int idx = ((u_e>>3)*64 + bge)*8 + (u_e&7);  // hA[koct][b][8] pairs
            if (LAYER==0) st4coh(hp0 + (s&3)*32768 + idx, pk);
            else {
                st4coh(hp1 + ((s+1)&1)*32768 + idx, pk);     // h1[s-1] -> slot (s-1)&1
                out[((size_t)bge*TT + t)*HH + u_e] = hn;     // fp32, plain cached
            }
        }

        // ---- publish: vmcnt(0) drain in syncthreads acks h stores first ----
        __syncthreads();
        if (tid==0) stslot(slots + myslot, s+1);
    }
#undef LOADH
#undef MATHH
}

__global__ void __launch_bounds__(512,1) lstm_persist(
    const float* __restrict__ x,
    const float* __restrict__ Wih0, const float* __restrict__ Whh0,
    const float* __restrict__ bi0,  const float* __restrict__ bh0,
    const float* __restrict__ Wih1, const float* __restrict__ Whh1,
    const float* __restrict__ bi1,  const float* __restrict__ bh1,
    unsigned* hp0, unsigned* hp1, float* out, int* slots)
{
    __shared__ SMem sm;
    const int layer = blockIdx.x>>7, lid = blockIdx.x&127;
    const int bg = lid>>5, tile_u = lid&31;
    if (layer==0) run<0>(x, Wih0, Whh0, bi0, bh0, hp0, hp1, out, slots, bg, tile_u, &sm);
    else          run<1>(x, Wih1, Whh1, bi1, bh1, hp0, hp1, out, slots, bg, tile_u, &sm);
}

extern "C" void kernel_launch(void* const* d_in, const int* in_sizes, int n_in,
                              void* d_out, int out_size, void* d_ws, size_t ws_size,
                              hipStream_t stream) {
    (void)in_sizes; (void)n_in; (void)out_size; (void)ws_size;
    const float* x    = (const float*)d_in[0];
    const float* Wih0 = (const float*)d_in[1];
    const float* Whh0 = (const float*)d_in[2];
    const float* bi0  = (const float*)d_in[3];
    const float* bh0  = (const float*)d_in[4];
    const float* Wih1 = (const float*)d_in[5];
    const float* Whh1 = (const float*)d_in[6];
    const float* bi1  = (const float*)d_in[7];
    const float* bh1  = (const float*)d_in[8];
    float* out = (float*)d_out;
    unsigned* ws = (unsigned*)d_ws;

    // ws (uints): hp0 ring[4][32768] | hp1 ring[2][32768] | slots[256]
    unsigned* hp0 = ws;                   // 4 slots x 128KB
    unsigned* hp1 = ws + 4*32768;         // 2 slots x 128KB
    int* slots    = (int*)(ws + 6*32768); // [bg:4][L0 tiles 0..31 | L1 tiles 0..31]

    hipMemsetAsync(d_ws, 0, (6*32768 + 256)*sizeof(unsigned), stream);

    void* args[] = {
        (void*)&x, (void*)&Wih0, (void*)&Whh0, (void*)&bi0, (void*)&bh0,
        (void*)&Wih1, (void*)&Whh1, (void*)&bi1, (void*)&bh1,
        (void*)&hp0, (void*)&hp1, (void*)&out, (void*)&slots
    };
    hipLaunchCooperativeKernel((const void*)lstm_persist, dim3(NB), dim3(512),
                               args, 0, stream);
}